// Round 2
// baseline (183.964 us; speedup 1.0000x reference)
//
#include <hip/hip_runtime.h>
#include <hip/hip_bf16.h>

// AttentionHead: out = softmax((q@Wq^T+bq) @ (k@Wk^T+bk)^T / 16) @ (v@Wv^T+bv)
// N=8192, DK=DV=256. f32 in/out, bf16 MFMA internally.
//
// ws layout:
//   [0,4M)    Qs  bf16 [8192][256]  (pre-scaled by 1/16)
//   [4M,8M)   Ks  bf16 [8192][256]
//   [8M,12M)  Vt  bf16 [256][8192]  (V transposed)
//   [12M,..)  Op  f32  [SPLIT][8192][256] (per-split unnormalized O)
//   [..,..)   Ml  float2 [SPLIT][8192]    (per-split m,l)
// SPLIT = 8 if ws_size allows (~76.6 MB), else 4.

typedef __attribute__((ext_vector_type(8))) short short8;
typedef __attribute__((ext_vector_type(4))) short short4v;
typedef __attribute__((ext_vector_type(4))) float f32x4;
typedef __attribute__((ext_vector_type(4))) float float4v;

#define MFMA16 __builtin_amdgcn_mfma_f32_16x16x32_bf16

namespace {
constexpr int kN  = 8192;
constexpr int kD  = 256;   // DK == DV == 256
constexpr int kQB = 128;   // q rows per flash block (4 waves x 32)
constexpr int kKVB = 64;   // kv rows per iteration
}

__device__ __forceinline__ unsigned short f2bf(float x) {
  union { float f; unsigned u; } v; v.f = x;
  unsigned r = v.u + 0x7FFFu + ((v.u >> 16) & 1u);  // RNE
  return (unsigned short)(r >> 16);
}

// ---------------------------------------------------------------------------
// proj: Y = X @ W^T + b, bf16 out.  mode 0: Qs (x 1/16); 1: Ks; 2: Vt (transposed)
// grid (128, 4, 3), block 256. Tile 64x64, K=256 staged whole in LDS.
// ---------------------------------------------------------------------------
__global__ __launch_bounds__(256) void proj_kernel(
    const float* __restrict__ qx, const float* __restrict__ kx, const float* __restrict__ vx,
    const float* __restrict__ Wq, const float* __restrict__ bq,
    const float* __restrict__ Wk, const float* __restrict__ bk,
    const float* __restrict__ Wv, const float* __restrict__ bv,
    short* __restrict__ Qs, short* __restrict__ Ks, short* __restrict__ Vt)
{
  const int mode = blockIdx.z;
  const float* X; const float* W; const float* B;
  if (mode == 0)      { X = qx; W = Wq; B = bq; }
  else if (mode == 1) { X = kx; W = Wk; B = bk; }
  else                { X = vx; W = Wv; B = bv; }

  const int nb = blockIdx.x * 64;
  const int ob = blockIdx.y * 64;

  __shared__ short XA[64][264];  // +8 pad
  __shared__ short WB[64][264];

  const int t  = threadIdx.x;
  {
    const int c4 = t & 63;       // float4 column
    const int r0 = t >> 6;       // 4 rows/pass
#pragma unroll
    for (int p = 0; p < 16; ++p) {
      const int r = p * 4 + r0;
      float4v xv = *(const float4v*)(X + (size_t)(nb + r) * kD + c4 * 4);
      float4v wv = *(const float4v*)(W + (size_t)(ob + r) * kD + c4 * 4);
      short4v xs, wsv;
#pragma unroll
      for (int j = 0; j < 4; ++j) { xs[j] = (short)f2bf(xv[j]); wsv[j] = (short)f2bf(wv[j]); }
      *(short4v*)(&XA[r][c4 * 4]) = xs;
      *(short4v*)(&WB[r][c4 * 4]) = wsv;
    }
  }
  __syncthreads();

  const int w  = t >> 6;
  const int l  = t & 63;
  const int lr = l & 15;
  const int g  = l >> 4;

  const f32x4 vzero = {0.f, 0.f, 0.f, 0.f};
  f32x4 acc[4];
#pragma unroll
  for (int ct = 0; ct < 4; ++ct) acc[ct] = vzero;

#pragma unroll
  for (int s = 0; s < 8; ++s) {
    short8 af = *(const short8*)(&XA[w * 16 + lr][s * 32 + g * 8]);
#pragma unroll
    for (int ct = 0; ct < 4; ++ct) {
      short8 bf = *(const short8*)(&WB[ct * 16 + lr][s * 32 + g * 8]);
      acc[ct] = MFMA16(af, bf, acc[ct], 0, 0, 0);
    }
  }

  // D layout: col = lane&15 (o), row = 4*(lane>>4)+reg (n)
#pragma unroll
  for (int ct = 0; ct < 4; ++ct) {
    const int o = ob + ct * 16 + lr;
    const float bias = B[o];
    if (mode == 2) {
      const int n0 = nb + w * 16 + g * 4;
      short4v vs;
#pragma unroll
      for (int r2 = 0; r2 < 4; ++r2) vs[r2] = (short)f2bf(acc[ct][r2] + bias);
      *(short4v*)(Vt + (size_t)o * kN + n0) = vs;   // 4 contiguous n: 8B store
    } else {
      short* Out = (mode == 0) ? Qs : Ks;
      const float sc = (mode == 0) ? 0.0625f : 1.0f;
#pragma unroll
      for (int r2 = 0; r2 < 4; ++r2) {
        const int n = nb + w * 16 + g * 4 + r2;
        Out[(size_t)n * kD + o] = (short)f2bf((acc[ct][r2] + bias) * sc);
      }
    }
  }
}

// ---------------------------------------------------------------------------
// flash: per block: 128 q rows (4 waves x 32), one kv split, KVB=64/iter.
// Swapped QK^T (S^T = K@Q^T) -> kv-reduction is 2 shfl_xor; P routes through
// a per-wave LDS buffer (no barrier needed) to become the PV A-operand.
// XOR-swizzled LDS (c ^= (row&7)<<3 in shorts), 72KB -> 2 blocks/CU.
// SPLIT=8: grid 512 (2 blocks/CU), one split per XCD.
// ---------------------------------------------------------------------------
template<int SPLIT>
__global__ __launch_bounds__(256, 2) void flash_kernel(
    const short* __restrict__ Qs, const short* __restrict__ Ks, const short* __restrict__ Vt,
    float* __restrict__ Op, float2* __restrict__ Ml)
{
  constexpr int kKVRange = kN / SPLIT;
  const int linear = (int)blockIdx.x + ((int)blockIdx.y << 6);
  int sp, qt;
  if (SPLIT == 8) {        // 512 blocks: one split per XCD, qt bijective
    sp = linear & 7;
    qt = linear >> 3;
  } else {                 // 256 blocks: 2 XCDs per split
    const int xcd = linear & 7;
    sp = xcd >> 1;
    qt = ((xcd & 1) << 5) + (linear >> 3);
  }
  const int kv_base = sp * kKVRange;

  __shared__ short KL[64 * 256];   // K tile  [kv][dk], swizzled
  __shared__ short VL[256 * 64];   // Vt tile [dv][kv], swizzled
  __shared__ short PL[4 * 16 * 64];// per-wave P [q][kv], swizzled, single-qs

  const int t = threadIdx.x;
  const int w = t >> 6, l = t & 63, lr = l & 15, g = l >> 4;

  // Q fragments in registers: 32 rows x 256 dk per wave (64 VGPR)
  short8 qf[2][8];
#pragma unroll
  for (int qs = 0; qs < 2; ++qs) {
    const size_t qrow = (size_t)qt * kQB + w * 32 + qs * 16 + lr;
#pragma unroll
    for (int s = 0; s < 8; ++s)
      qf[qs][s] = *(const short8*)(Qs + qrow * kD + s * 32 + g * 8);
  }

  const f32x4 vzero = {0.f, 0.f, 0.f, 0.f};
  f32x4 oacc[2][16];
#pragma unroll
  for (int qs = 0; qs < 2; ++qs)
#pragma unroll
    for (int dvt = 0; dvt < 16; ++dvt) oacc[qs][dvt] = vzero;
  float m_reg[2] = {-1e30f, -1e30f};
  float l_reg[2] = {0.f, 0.f};

  const int cK = t & 31, rK = t >> 5;   // K stage: 32 thr/row
  const int cV = t & 7,  rV = t >> 3;   // V stage: 8 thr/row

  for (int it = 0; it < kKVRange / kKVB; ++it) {
    const int kv0 = kv_base + it * kKVB;
    __syncthreads();  // protect LDS reuse from previous iteration
#pragma unroll
    for (int p = 0; p < 8; ++p) {
      const int r = p * 8 + rK;
      *(short8*)(&KL[r * 256 + ((cK * 8) ^ ((r & 7) << 3))]) =
          *(const short8*)(Ks + (size_t)(kv0 + r) * kD + cK * 8);
    }
#pragma unroll
    for (int p = 0; p < 8; ++p) {
      const int dv = p * 32 + rV;
      *(short8*)(&VL[dv * 64 + ((cV * 8) ^ ((dv & 7) << 3))]) =
          *(const short8*)(Vt + (size_t)dv * kN + kv0 + cV * 8);
    }
    __syncthreads();

    // ---- QK^T: S^T[kv][q], 4 kv-tiles x 2 q-subtiles, K frag reused x2 ----
    f32x4 sacc[4][2];
#pragma unroll
    for (int tt = 0; tt < 4; ++tt) { sacc[tt][0] = vzero; sacc[tt][1] = vzero; }
    __builtin_amdgcn_s_setprio(1);
#pragma unroll
    for (int tt = 0; tt < 4; ++tt) {
      const int row = tt * 16 + lr;
#pragma unroll
      for (int s = 0; s < 8; ++s) {
        short8 kf = *(const short8*)(&KL[row * 256 + ((s * 32 + g * 8) ^ ((row & 7) << 3))]);
        sacc[tt][0] = MFMA16(kf, qf[0][s], sacc[tt][0], 0, 0, 0);
        sacc[tt][1] = MFMA16(kf, qf[1][s], sacc[tt][1], 0, 0, 0);
      }
    }
    __builtin_amdgcn_s_setprio(0);

    // ---- online softmax per q column (q = lr); lane's S^T rows: kv=16t+4g+r
    // defer-max (T13): skip rescale while per-tile max growth <= 8.
    short8 pa[2][2];
#pragma unroll
    for (int qs = 0; qs < 2; ++qs) {
      float pmax = -1e30f;
#pragma unroll
      for (int tt = 0; tt < 4; ++tt)
#pragma unroll
        for (int r2 = 0; r2 < 4; ++r2) pmax = fmaxf(pmax, sacc[tt][qs][r2]);
      pmax = fmaxf(pmax, __shfl_xor(pmax, 16));
      pmax = fmaxf(pmax, __shfl_xor(pmax, 32));
      const bool skip = __all(pmax - m_reg[qs] <= 8.f);
      const float newm = skip ? m_reg[qs] : fmaxf(m_reg[qs], pmax);
      float psum = 0.f;
#pragma unroll
      for (int tt = 0; tt < 4; ++tt) {
        short4v ps;
#pragma unroll
        for (int r2 = 0; r2 < 4; ++r2) {
          const float p = __expf(sacc[tt][qs][r2] - newm);
          psum += p;
          ps[r2] = (short)f2bf(p);
        }
        // P[q=lr][kv=tt*16+g*4+r2], swizzled (8B store, XOR flips bits>=3)
        *(short4v*)(&PL[(w * 16 + lr) * 64 + ((tt * 16 + g * 4) ^ ((lr & 7) << 3))]) = ps;
      }
      psum += __shfl_xor(psum, 16);
      psum += __shfl_xor(psum, 32);
      if (!skip) {
        const float corr = __expf(m_reg[qs] - newm);  // first iter: 0
        l_reg[qs] = l_reg[qs] * corr + psum;
        m_reg[qs] = newm;
        // O rescale: O rows are q=4g+r2; fetch corr for those q via shfl
        f32x4 cs;
#pragma unroll
        for (int r2 = 0; r2 < 4; ++r2) cs[r2] = __shfl(corr, (g * 4 + r2) + (l & 48));
        // note: corr is uniform across the 4 g-groups for a given lr, so
        // source lane (g*4+r2) within any 16-group works; use group base 0.
#pragma unroll
        for (int r2 = 0; r2 < 4; ++r2) cs[r2] = __shfl(corr, g * 4 + r2);
#pragma unroll
        for (int dvt = 0; dvt < 16; ++dvt) oacc[qs][dvt] *= cs;
      } else {
        l_reg[qs] += psum;
      }
      // read this qs's PV A-fragments before next qs overwrites PL (in-wave
      // DS ordering; no barrier needed)
#pragma unroll
      for (int ks = 0; ks < 2; ++ks)
        pa[qs][ks] = *(const short8*)(
            &PL[(w * 16 + lr) * 64 + ((ks * 32 + g * 8) ^ ((lr & 7) << 3))]);
    }

    // ---- PV: O[q][dv] += P @ V ----
    __builtin_amdgcn_s_setprio(1);
#pragma unroll
    for (int dvt = 0; dvt < 16; ++dvt) {
      const int row = dvt * 16 + lr;
#pragma unroll
      for (int ks = 0; ks < 2; ++ks) {
        short8 vb = *(const short8*)(&VL[row * 64 + ((ks * 32 + g * 8) ^ ((row & 7) << 3))]);
        oacc[0][dvt] = MFMA16(pa[0][ks], vb, oacc[0][dvt], 0, 0, 0);
        oacc[1][dvt] = MFMA16(pa[1][ks], vb, oacc[1][dvt], 0, 0, 0);
      }
    }
    __builtin_amdgcn_s_setprio(0);
  }

  // ---- per-split partials ----
#pragma unroll
  for (int qs = 0; qs < 2; ++qs)
#pragma unroll
    for (int dvt = 0; dvt < 16; ++dvt)
#pragma unroll
      for (int r2 = 0; r2 < 4; ++r2) {
        const size_t qrow = (size_t)qt * kQB + w * 32 + qs * 16 + g * 4 + r2;
        Op[((size_t)sp * kN + qrow) * kD + dvt * 16 + lr] = oacc[qs][dvt][r2];
      }
  if (g == 0) {
#pragma unroll
    for (int qs = 0; qs < 2; ++qs) {
      const size_t qrow = (size_t)qt * kQB + w * 32 + qs * 16 + lr;
      Ml[(size_t)sp * kN + qrow] = make_float2(m_reg[qs], l_reg[qs]);
    }
  }
}

// ---------------------------------------------------------------------------
// merge: combine SPLIT partials per q row and normalize. grid 8192, block 256.
// ---------------------------------------------------------------------------
template<int SPLIT>
__global__ __launch_bounds__(256) void merge_kernel(
    const float* __restrict__ Op, const float2* __restrict__ Ml, float* __restrict__ out)
{
  const int qrow = blockIdx.x;
  const int d = threadIdx.x;
  float m[SPLIT], li[SPLIT];
  float M = -1e30f;
#pragma unroll
  for (int s = 0; s < SPLIT; ++s) {
    const float2 a = Ml[(size_t)s * kN + qrow];
    m[s] = a.x; li[s] = a.y;
    M = fmaxf(M, m[s]);
  }
  float L = 0.f, accv = 0.f;
#pragma unroll
  for (int s = 0; s < SPLIT; ++s) {
    const float wgt = __expf(m[s] - M);
    L += wgt * li[s];
    accv += wgt * Op[((size_t)s * kN + qrow) * kD + d];
  }
  out[(size_t)qrow * kD + d] = accv / L;
}

// ---------------------------------------------------------------------------
extern "C" void kernel_launch(void* const* d_in, const int* in_sizes, int n_in,
                              void* d_out, int out_size, void* d_ws, size_t ws_size,
                              hipStream_t stream)
{
  const float* q  = (const float*)d_in[0];
  const float* k  = (const float*)d_in[1];
  const float* v  = (const float*)d_in[2];
  const float* Wq = (const float*)d_in[3];
  const float* bq = (const float*)d_in[4];
  const float* Wk = (const float*)d_in[5];
  const float* bk = (const float*)d_in[6];
  const float* Wv = (const float*)d_in[7];
  const float* bv = (const float*)d_in[8];
  // d_in[9] = seq_len (unused: full-row softmax over all N tokens)

  char* ws = (char*)d_ws;
  short*  Qs = (short*)(ws);
  short*  Ks = (short*)(ws + ((size_t)4 << 20));
  short*  Vt = (short*)(ws + ((size_t)8 << 20));
  const size_t opOff = (size_t)12 << 20;
  float*  Op = (float*)(ws + opOff);

  proj_kernel<<<dim3(kN / 64, kD / 64, 3), 256, 0, stream>>>(
      q, k, v, Wq, bq, Wk, bk, Wv, bv, Qs, Ks, Vt);

  const size_t opBytes8 = (size_t)8 * kN * kD * 4;
  const size_t need8 = opOff + opBytes8 + (size_t)8 * kN * 8;
  if (ws_size >= need8) {
    float2* Ml = (float2*)(ws + opOff + opBytes8);
    flash_kernel<8><<<dim3(64, 8), 256, 0, stream>>>(Qs, Ks, Vt, Op, Ml);
    merge_kernel<8><<<dim3(kN), 256, 0, stream>>>(Op, Ml, (float*)d_out);
  } else {
    const size_t opBytes4 = (size_t)4 * kN * kD * 4;
    float2* Ml = (float2*)(ws + opOff + opBytes4);
    flash_kernel<4><<<dim3(64, 4), 256, 0, stream>>>(Qs, Ks, Vt, Op, Ml);
    merge_kernel<4><<<dim3(kN), 256, 0, stream>>>(Op, Ml, (float*)d_out);
  }
}

// Round 3
// 112.445 us; speedup vs baseline: 1.6360x; 1.6360x over previous
//
#include <hip/hip_runtime.h>
#include <hip/hip_bf16.h>

// AttentionHead: out = softmax((q@Wq^T+bq) @ (k@Wk^T+bk)^T / 16) @ (v@Wv^T+bv)
// N=8192, DK=DV=256. f32 in/out, bf16 32x32x16 MFMA internally.
//
// ws layout:
//   [0,4M)    Qimg bf16 — Q in QK B-fragment image order (pre-scaled 1/16)
//   [4M,8M)   Kimg bf16 — K in QK A-fragment image order
//   [8M,12M)  Vimg bf16 — V in PV B-fragment image order
//   [12M,..)  Op  f32  [SPLIT][8192][256]
//   [..]      Ml  float2 [SPLIT][8192]
//
// Image layouts (per 32-row kv/q block = 8192 shorts = 16 KB):
//   Kimg/Qimg: idx(r,k) = (r>>5)*8192 + (k>>4)*512 + ((k>>3)&1)*256 + (r&31)*8 + (k&7)
//   Vimg:      idx(kv,dv)= (kv>>5)*8192 + (dv>>5)*1024 + ((kv>>4)&1)*512
//                          + ((kv>>3)&1)*256 + (dv&31)*8 + (kv&7)
// These make LDS staging (global_load_lds) and all ds_read_b128 lane-linear.

typedef __attribute__((ext_vector_type(8))) short short8;
typedef __attribute__((ext_vector_type(4))) short short4v;
typedef __attribute__((ext_vector_type(4))) float f32x4;
typedef __attribute__((ext_vector_type(4))) float float4v;
typedef __attribute__((ext_vector_type(16))) float f32x16;

#define MFMA16 __builtin_amdgcn_mfma_f32_16x16x32_bf16
#define MFMA32 __builtin_amdgcn_mfma_f32_32x32x16_bf16

namespace {
constexpr int kN = 8192;
constexpr int kD = 256;
constexpr int kKVB = 32;   // kv rows per flash iteration
}

__device__ __forceinline__ unsigned short f2bf(float x) {
  union { float f; unsigned u; } v; v.f = x;
  unsigned r = v.u + 0x7FFFu + ((v.u >> 16) & 1u);  // RNE
  return (unsigned short)(r >> 16);
}

__device__ __forceinline__ unsigned cvtpk_bf16(float lo, float hi) {
  unsigned d;
  asm("v_cvt_pk_bf16_f32 %0, %1, %2" : "=v"(d) : "v"(lo), "v"(hi));
  return d;
}

__device__ __forceinline__ void gll16(const short* g, short* lp) {
  __builtin_amdgcn_global_load_lds(
      (const __attribute__((address_space(1))) void*)g,
      (__attribute__((address_space(3))) void*)lp, 16, 0, 0);
}

// ---------------------------------------------------------------------------
// proj: Y = X @ W^T + b -> fragment-image layouts.
// mode 0: Qimg (x 1/16); 1: Kimg; 2: Vimg. grid (128,4,3), block 256.
// ---------------------------------------------------------------------------
__global__ __launch_bounds__(256) void proj_kernel(
    const float* __restrict__ qx, const float* __restrict__ kx, const float* __restrict__ vx,
    const float* __restrict__ Wq, const float* __restrict__ bq,
    const float* __restrict__ Wk, const float* __restrict__ bk,
    const float* __restrict__ Wv, const float* __restrict__ bv,
    short* __restrict__ Qimg, short* __restrict__ Kimg, short* __restrict__ Vimg)
{
  const int mode = blockIdx.z;
  const float* X; const float* W; const float* B;
  if (mode == 0)      { X = qx; W = Wq; B = bq; }
  else if (mode == 1) { X = kx; W = Wk; B = bk; }
  else                { X = vx; W = Wv; B = bv; }

  const int nb = blockIdx.x * 64;
  const int ob = blockIdx.y * 64;

  __shared__ short XA[64][264];
  __shared__ short WB[64][264];

  const int t  = threadIdx.x;
  {
    const int c4 = t & 63;
    const int r0 = t >> 6;
#pragma unroll
    for (int p = 0; p < 16; ++p) {
      const int r = p * 4 + r0;
      float4v xv = *(const float4v*)(X + (size_t)(nb + r) * kD + c4 * 4);
      float4v wv = *(const float4v*)(W + (size_t)(ob + r) * kD + c4 * 4);
      short4v xs, wsv;
#pragma unroll
      for (int j = 0; j < 4; ++j) { xs[j] = (short)f2bf(xv[j]); wsv[j] = (short)f2bf(wv[j]); }
      *(short4v*)(&XA[r][c4 * 4]) = xs;
      *(short4v*)(&WB[r][c4 * 4]) = wsv;
    }
  }
  __syncthreads();

  const int w  = t >> 6;
  const int l  = t & 63;
  const int lr = l & 15;
  const int g  = l >> 4;

  const f32x4 vzero = {0.f, 0.f, 0.f, 0.f};
  f32x4 acc[4];
#pragma unroll
  for (int ct = 0; ct < 4; ++ct) acc[ct] = vzero;

#pragma unroll
  for (int s = 0; s < 8; ++s) {
    short8 af = *(const short8*)(&XA[w * 16 + lr][s * 32 + g * 8]);
#pragma unroll
    for (int ct = 0; ct < 4; ++ct) {
      short8 bf = *(const short8*)(&WB[ct * 16 + lr][s * 32 + g * 8]);
      acc[ct] = MFMA16(af, bf, acc[ct], 0, 0, 0);
    }
  }

  // D layout (16x16): col = lane&15 (-> o), row = 4*(lane>>4)+reg (-> n)
#pragma unroll
  for (int ct = 0; ct < 4; ++ct) {
    const int o = ob + ct * 16 + lr;
    const float bias = B[o];
    if (mode == 2) {
      // Vimg: 4 consecutive kv (=n) share all index bits except kv&7
      const int n0 = nb + w * 16 + g * 4;
      short4v vs;
#pragma unroll
      for (int r2 = 0; r2 < 4; ++r2) vs[r2] = (short)f2bf(acc[ct][r2] + bias);
      const size_t idx = (size_t)(n0 >> 5) * 8192 + (size_t)(o >> 5) * 1024
                       + (size_t)((n0 >> 4) & 1) * 512 + (size_t)((n0 >> 3) & 1) * 256
                       + (size_t)(o & 31) * 8 + (n0 & 7);
      *(short4v*)(Vimg + idx) = vs;
    } else {
      short* Out = (mode == 0) ? Qimg : Kimg;
      const float sc = (mode == 0) ? 0.0625f : 1.0f;
#pragma unroll
      for (int r2 = 0; r2 < 4; ++r2) {
        const int n = nb + w * 16 + g * 4 + r2;
        const size_t idx = (size_t)(n >> 5) * 8192 + (size_t)(o >> 4) * 512
                         + (size_t)((o >> 3) & 1) * 256 + (size_t)(n & 31) * 8 + (o & 7);
        Out[idx] = (short)f2bf((acc[ct][r2] + bias) * sc);
      }
    }
  }
}

// ---------------------------------------------------------------------------
// flash: 512 threads = 8 waves, each wave owns 32 q rows (block = 256 q).
// Swapped QK^T (S^T = K@Q^T, 32x32): q is lane-local (q = lane&31).
// P redistributed in-register (cvt_pk + shfl_xor 32) -> PV A-operand.
// K/V double-buffered in LDS via global_load_lds from fragment images.
// grid = 32*SPLIT blocks; sp aligned to XCD.
// ---------------------------------------------------------------------------
template<int SPLIT>
__global__ __launch_bounds__(512) void flash_kernel(
    const short* __restrict__ Qimg, const short* __restrict__ Kimg, const short* __restrict__ Vimg,
    float* __restrict__ Op, float2* __restrict__ Ml)
{
  constexpr int kIters = (kN / SPLIT) / kKVB;
  const int linear = (int)blockIdx.x;
  int sp, qb;
  if (SPLIT == 8) { sp = linear & 7; qb = linear >> 3; }
  else { const int xcd = linear & 7; sp = xcd >> 1; qb = ((linear >> 3) << 1) | (xcd & 1); }
  const int kvblk0 = sp * (kN / SPLIT / 32);

  __shared__ short sbuf[2][2][8192];  // [dbuf][K/V][16KB tile]

  const int t = threadIdx.x;
  const int w = t >> 6, l = t & 63;
  const int hf = l >> 5;          // lane half
  const int lc = l & 31;          // lane col

  // prologue: stage iter 0 into buf 0 (2 passes K + 2 passes V)
  {
    const short* kg = Kimg + (size_t)kvblk0 * 8192 + w * 512 + l * 8;
    const short* vg = Vimg + (size_t)kvblk0 * 8192 + w * 512 + l * 8;
    gll16(kg,        &sbuf[0][0][w * 512]);
    gll16(kg + 4096, &sbuf[0][0][4096 + w * 512]);
    gll16(vg,        &sbuf[0][1][w * 512]);
    gll16(vg + 4096, &sbuf[0][1][4096 + w * 512]);
  }

  // Q fragments: 16 ksteps x short8 (64 VGPR)
  short8 qf[16];
  {
    const short* qsrc = Qimg + (size_t)(qb * 8 + w) * 8192 + l * 8;
#pragma unroll
    for (int ks = 0; ks < 16; ++ks) qf[ks] = *(const short8*)(qsrc + ks * 512);
  }

  f32x16 oacc[8];
#pragma unroll
  for (int dvt = 0; dvt < 8; ++dvt)
#pragma unroll
    for (int r = 0; r < 16; ++r) oacc[dvt][r] = 0.f;
  float mr = -1e30f, lsum = 0.f;

  asm volatile("s_waitcnt vmcnt(0)" ::: "memory");
  __syncthreads();

  for (int it = 0; it < kIters; ++it) {
    const int cur = it & 1;
    // prefetch next tile into the other buffer (T14: issue early)
    if (it + 1 < kIters) {
      const short* kg = Kimg + (size_t)(kvblk0 + it + 1) * 8192 + w * 512 + l * 8;
      const short* vg = Vimg + (size_t)(kvblk0 + it + 1) * 8192 + w * 512 + l * 8;
      short* kb = &sbuf[cur ^ 1][0][0];
      short* vb = &sbuf[cur ^ 1][1][0];
      gll16(kg,        kb + w * 512);
      gll16(kg + 4096, kb + 4096 + w * 512);
      gll16(vg,        vb + w * 512);
      gll16(vg + 4096, vb + 4096 + w * 512);
    }

    // ---- QK^T: S^T[32 kv][32 q], 16 ksteps ----
    f32x16 sacc;
#pragma unroll
    for (int r = 0; r < 16; ++r) sacc[r] = 0.f;
    __builtin_amdgcn_s_setprio(1);
#pragma unroll
    for (int ks = 0; ks < 16; ++ks) {
      short8 kf = *(const short8*)(&sbuf[cur][0][ks * 512 + l * 8]);
      sacc = MFMA32(kf, qf[ks], sacc, 0, 0, 0);
    }
    __builtin_amdgcn_s_setprio(0);

    // ---- online softmax (q = lane&31; lane holds 16 of 32 kv) ----
    float pmax = sacc[0];
#pragma unroll
    for (int r = 1; r < 16; ++r) pmax = fmaxf(pmax, sacc[r]);
    pmax = fmaxf(pmax, __shfl_xor(pmax, 32));
    const bool noskip = !__all(pmax - mr <= 8.f);   // T13 defer-max
    if (noskip) {
      const float newm = fmaxf(mr, pmax);
      const float corr = __expf(mr - newm);  // first iter: 0
      mr = newm;
      lsum *= corr;
      // O rows are q' = (r&3)+8*(r>>2)+4*hf; corr for q' lives in lane q'
#pragma unroll
      for (int r = 0; r < 16; ++r) {
        const float c = __shfl(corr, (r & 3) + 8 * (r >> 2) + 4 * hf);
#pragma unroll
        for (int dvt = 0; dvt < 8; ++dvt) oacc[dvt][r] *= c;
      }
    }
    float psum = 0.f;
#pragma unroll
    for (int r = 0; r < 16; ++r) { sacc[r] = __expf(sacc[r] - mr); psum += sacc[r]; }
    psum += __shfl_xor(psum, 32);
    lsum += psum;

    // ---- pack P -> PV A-fragments (in-register, T12) ----
    // have: kv = (r&3)+8*(r>>2)+4*hf ; need: kv = ks2*16 + 8*hf + e
    short8 pa[2];
#pragma unroll
    for (int w2 = 0; w2 < 2; ++w2) {
      const int b = w2 * 8;
      const unsigned A0 = cvtpk_bf16(sacc[b + 0], sacc[b + 1]);
      const unsigned A1 = cvtpk_bf16(sacc[b + 2], sacc[b + 3]);
      const unsigned B0 = cvtpk_bf16(sacc[b + 4], sacc[b + 5]);
      const unsigned B1 = cvtpk_bf16(sacc[b + 6], sacc[b + 7]);
      const unsigned sA0 = (unsigned)__shfl_xor((int)A0, 32);
      const unsigned sA1 = (unsigned)__shfl_xor((int)A1, 32);
      const unsigned sB0 = (unsigned)__shfl_xor((int)B0, 32);
      const unsigned sB1 = (unsigned)__shfl_xor((int)B1, 32);
      union { unsigned u[4]; short8 s; } pu;
      pu.u[0] = hf ? sB0 : A0;
      pu.u[1] = hf ? sB1 : A1;
      pu.u[2] = hf ? B0 : sA0;
      pu.u[3] = hf ? B1 : sA1;
      pa[w2] = pu.s;
    }

    // ---- PV: O[32 q][256 dv] += P @ V ----
    __builtin_amdgcn_s_setprio(1);
#pragma unroll
    for (int dvt = 0; dvt < 8; ++dvt) {
#pragma unroll
      for (int ks2 = 0; ks2 < 2; ++ks2) {
        short8 vf = *(const short8*)(&sbuf[cur][1][(dvt * 2 + ks2) * 512 + l * 8]);
        oacc[dvt] = MFMA32(pa[ks2], vf, oacc[dvt], 0, 0, 0);
      }
    }
    __builtin_amdgcn_s_setprio(0);

    asm volatile("s_waitcnt vmcnt(0)" ::: "memory");  // prefetch landed (issued pre-QK)
    __syncthreads();
  }

  // ---- per-split partials ----
  const int qrow0 = qb * 256 + w * 32;
#pragma unroll
  for (int dvt = 0; dvt < 8; ++dvt)
#pragma unroll
    for (int r = 0; r < 16; ++r) {
      const int q = qrow0 + (r & 3) + 8 * (r >> 2) + 4 * hf;
      Op[((size_t)sp * kN + q) * kD + dvt * 32 + lc] = oacc[dvt][r];
    }
  if (l < 32) Ml[(size_t)sp * kN + qrow0 + l] = make_float2(mr, lsum);
}

// ---------------------------------------------------------------------------
// merge: combine SPLIT partials per q row and normalize. grid 8192, block 256.
// ---------------------------------------------------------------------------
template<int SPLIT>
__global__ __launch_bounds__(256) void merge_kernel(
    const float* __restrict__ Op, const float2* __restrict__ Ml, float* __restrict__ out)
{
  const int qrow = blockIdx.x;
  const int d = threadIdx.x;
  float m[SPLIT], li[SPLIT];
  float M = -1e30f;
#pragma unroll
  for (int s = 0; s < SPLIT; ++s) {
    const float2 a = Ml[(size_t)s * kN + qrow];
    m[s] = a.x; li[s] = a.y;
    M = fmaxf(M, m[s]);
  }
  float L = 0.f, accv = 0.f;
#pragma unroll
  for (int s = 0; s < SPLIT; ++s) {
    const float wgt = __expf(m[s] - M);
    L += wgt * li[s];
    accv += wgt * Op[((size_t)s * kN + qrow) * kD + d];
  }
  out[(size_t)qrow * kD + d] = accv / L;
}

// ---------------------------------------------------------------------------
extern "C" void kernel_launch(void* const* d_in, const int* in_sizes, int n_in,
                              void* d_out, int out_size, void* d_ws, size_t ws_size,
                              hipStream_t stream)
{
  const float* q  = (const float*)d_in[0];
  const float* k  = (const float*)d_in[1];
  const float* v  = (const float*)d_in[2];
  const float* Wq = (const float*)d_in[3];
  const float* bq = (const float*)d_in[4];
  const float* Wk = (const float*)d_in[5];
  const float* bk = (const float*)d_in[6];
  const float* Wv = (const float*)d_in[7];
  const float* bv = (const float*)d_in[8];

  char* ws = (char*)d_ws;
  short* Qimg = (short*)(ws);
  short* Kimg = (short*)(ws + ((size_t)4 << 20));
  short* Vimg = (short*)(ws + ((size_t)8 << 20));
  const size_t opOff = (size_t)12 << 20;
  float* Op = (float*)(ws + opOff);

  proj_kernel<<<dim3(kN / 64, kD / 64, 3), 256, 0, stream>>>(
      q, k, v, Wq, bq, Wk, bk, Wv, bv, Qimg, Kimg, Vimg);

  const size_t opBytes8 = (size_t)8 * kN * kD * 4;
  const size_t need8 = opOff + opBytes8 + (size_t)8 * kN * 8;
  if (ws_size >= need8) {
    float2* Ml = (float2*)(ws + opOff + opBytes8);
    flash_kernel<8><<<dim3(256), 512, 0, stream>>>(Qimg, Kimg, Vimg, Op, Ml);
    merge_kernel<8><<<dim3(kN), 256, 0, stream>>>(Op, Ml, (float*)d_out);
  } else {
    const size_t opBytes4 = (size_t)4 * kN * kD * 4;
    float2* Ml = (float2*)(ws + opOff + opBytes4);
    flash_kernel<4><<<dim3(128), 512, 0, stream>>>(Qimg, Kimg, Vimg, Op, Ml);
    merge_kernel<4><<<dim3(kN), 256, 0, stream>>>(Op, Ml, (float*)d_out);
  }
}